// Round 18
// baseline (2681.857 us; speedup 1.0000x reference)
//
#include <hip/hip_runtime.h>
#include <hip/hip_bf16.h>

// Geometry constants
#define NPHI 720
#define NT   512
#define NH   256
#define NB   32

#define DPHI_F   0.004363323129985824f   // pi/720
#define INV_DT_F 181.01933598375618f     // 256/sqrt(2)
#define DX_F     0.0078125f              // 2/256
#define W2PI_F   0.012271846303085130f   // 2*pi/512

#define FSTR 520   // padded filt row stride (4 zero | 512 data | 4 zero)

typedef __fp16  h2   __attribute__((ext_vector_type(2)));   // cvt_pkrtz return type
typedef _Float16 f16x2 __attribute__((ext_vector_type(2))); // fdot2 operand type
typedef _Float16 f16x8 __attribute__((ext_vector_type(8))); // mfma A/B operand
typedef float    f32x4 __attribute__((ext_vector_type(4))); // mfma C/D
typedef float    f32x4u __attribute__((ext_vector_type(4), aligned(4)));
typedef float    f32x2u __attribute__((ext_vector_type(2), aligned(4)));

__device__ __forceinline__ float fdot2f(h2 a, float b_bits, float c) {
    return __builtin_amdgcn_fdot2(__builtin_bit_cast(f16x2, a),
                                  __builtin_bit_cast(f16x2, b_bits), c, false);
}

// ---------------------------------------------------------------------------
// Front kernel (R16-measured, verbatim): GEMM filtering + all setup.
//  blocks [0,360):   GEMM 64(M) x 512(N) x 32(K), circulant B built ONCE in
//                    LDS from locally-computed h; A staged per k-step.
//  blocks [360,362): trig table   [362,426): zero out   [426,490): zero pads
// ---------------------------------------------------------------------------
#define ASTR 40
#define BSTR 40

__global__ __launch_bounds__(512) void front_kernel(const float* __restrict__ g,
                                                    const float* __restrict__ kern,
                                                    float* __restrict__ ws,
                                                    float4* __restrict__ out4,
                                                    float* __restrict__ filt) {
    __shared__ __attribute__((aligned(16))) unsigned short As[64 * ASTR];   // 5.12 KB
    __shared__ __attribute__((aligned(16))) unsigned short Bs[512 * BSTR];  // 40 KB
    __shared__ float hloc[512];
    const int bid = (int)blockIdx.x;
    const int tid = threadIdx.x;

    if (bid < 360) {
        // ---- prologue: h = irfft(K,512), then circulant Bs (once) ----
        float* ctab = (float*)As;        // 2 KB alias, dead after prologue
        float* kkp  = (float*)Bs;        // 1 KB alias, dead after prologue
        if (tid < 257) kkp[tid] = kern[tid];
        ctab[tid] = cosf((float)tid * W2PI_F);
        __syncthreads();
        {
            float acc = 0.f;
            for (int k = 1; k < 256; ++k)
                acc += kkp[k] * ctab[(k * tid) & 511];
            hloc[tid] = (kkp[0] + ((tid & 1) ? -kkp[256] : kkp[256]) + 2.f * acc)
                        * (1.f / 512.f);
        }
        __syncthreads();
        {   // Bs row d = tid: Bs[d][m] = h[(d-m)&511], packed fp16 pairs
            unsigned int uu[16];
            #pragma unroll
            for (int q = 0; q < 16; ++q) {
                float lo = hloc[(tid - 2 * q) & 511];
                float hi = hloc[(tid - 2 * q - 1) & 511];
                h2 p = __builtin_amdgcn_cvt_pkrtz(lo, hi);
                uu[q] = __builtin_bit_cast(unsigned int, p);
            }
            unsigned int* dst = (unsigned int*)&Bs[tid * BSTR];
            *(uint4*)(dst)      = make_uint4(uu[0], uu[1], uu[2], uu[3]);
            *(uint4*)(dst + 4)  = make_uint4(uu[4], uu[5], uu[6], uu[7]);
            *(uint4*)(dst + 8)  = make_uint4(uu[8], uu[9], uu[10], uu[11]);
            *(uint4*)(dst + 12) = make_uint4(uu[12], uu[13], uu[14], uu[15]);
        }

        // ---- GEMM ----
        const int m0 = bid * 64;
        const int w = tid >> 6, l = tid & 63;
        const int wm = (w >> 2) * 32;          // 0 or 32
        const int wn = (w & 3) * 128;          // 0,128,256,384
        const int fr = l & 15, g16 = l >> 4;
        const int arow = tid >> 3, aq = (tid & 7) * 4;

        f32x4 acc[2][8];
        #pragma unroll
        for (int i = 0; i < 2; ++i)
            #pragma unroll
            for (int j = 0; j < 8; ++j) acc[i][j] = (f32x4){0.f, 0.f, 0.f, 0.f};

        for (int k0 = 0; k0 < 512; k0 += 32) {
            __syncthreads();
            {   // stage A: 64 rows x 32 fp16
                const float* src = g + (size_t)(m0 + arow) * NT + (k0 + aq);
                float4 v = *(const float4*)src;
                h2 p0 = __builtin_amdgcn_cvt_pkrtz(v.x, v.y);
                h2 p1 = __builtin_amdgcn_cvt_pkrtz(v.z, v.w);
                *(uint2*)&As[arow * ASTR + aq] =
                    make_uint2(__builtin_bit_cast(unsigned int, p0),
                               __builtin_bit_cast(unsigned int, p1));
            }
            __syncthreads();

            f16x8 af[2], bf[8];
            #pragma unroll
            for (int i = 0; i < 2; ++i)
                af[i] = *(const f16x8*)&As[(wm + i * 16 + fr) * ASTR + g16 * 8];
            const int rbase = (wn + fr - k0) & 511;
            #pragma unroll
            for (int j = 0; j < 8; ++j) {
                const int row = (rbase + j * 16) & 511;
                bf[j] = *(const f16x8*)&Bs[row * BSTR + g16 * 8];
            }
            #pragma unroll
            for (int i = 0; i < 2; ++i)
                #pragma unroll
                for (int j = 0; j < 8; ++j)
                    acc[i][j] = __builtin_amdgcn_mfma_f32_16x16x32_f16(af[i], bf[j], acc[i][j], 0, 0, 0);
        }

        #pragma unroll
        for (int i = 0; i < 2; ++i)
            #pragma unroll
            for (int j = 0; j < 8; ++j)
                #pragma unroll
                for (int v = 0; v < 4; ++v) {
                    int row = m0 + wm + i * 16 + g16 * 4 + v;
                    int col = wn + j * 16 + fr;
                    filt[(size_t)row * FSTR + 4 + col] = acc[i][j][v];
                }
    } else if (bid < 362) {
        int p = (bid - 360) * 512 + tid;
        if (p < NPHI) {
            float ang = ((float)p + 0.5f) * DPHI_F;
            float s, c;
            sincosf(ang, &s, &c);
            float cd = c * INV_DT_F;
            float sd = s * INV_DT_F;
            ws[512 + 4 * p + 0] = cd;
            ws[512 + 4 * p + 1] = sd;
            ws[512 + 4 * p + 2] = cd * DX_F;
            ws[512 + 4 * p + 3] = sd * DX_F;
        }
    } else if (bid < 426) {
        const float4 z = make_float4(0.f, 0.f, 0.f, 0.f);
        const int nout4 = NB * NH * NH / 4;            // 524288
        for (int i = (bid - 362) * 512 + tid; i < nout4; i += 64 * 512)
            out4[i] = z;
    } else {
        const float4 z = make_float4(0.f, 0.f, 0.f, 0.f);
        const int nslots = 23040 * 2;                  // 46080
        for (int i = (bid - 426) * 512 + tid; i < nslots; i += 64 * 512) {
            int row = i >> 1;
            float* p = filt + (size_t)row * FSTR + ((i & 1) ? 516 : 0);
            *(float4*)p = z;
        }
    }
}

// ---------------------------------------------------------------------------
// Kernel C: backprojection v12 -- ping-pong win buffer, 1 barrier/sub-chunk.
// Grid = 6 angle-sixths x 4 batch-octs x 64 tiles = 1536 blocks (6/CU;
// LDS 21KB).  WCHUNK=4 (30 sub-chunks of 4 angles).
// win[buf][pp][a*WSTR+s] = {lo,hi of batch 2pp | 2pp+1} fp16 (8B).
// Pipeline per sub-chunk: LOADREGS(c+1) issue -> COMPUTE(buf[c&1]) ->
// WRITE_LDS(buf[(c+1)&1]) (vmcnt wait lands here, hidden by compute;
// writes overlap other waves' compute -- different buffer) -> barrier.
// Staging: wave-coherent -- sa=tid>>6 (wave=angle), sg=(tid>>4)&3
// (batch-pair), st=tid&15 (<14).  12 landing f32/thread.
// Index convention (R1/R3/R4-verified): ip = floor(q + cst), cst = 256.5-b0.
// ---------------------------------------------------------------------------
#define WCHUNK 4
#define WSTR   82
#define WREG   (WCHUNK * WSTR)    // 328 float2 per region per buffer

__global__ __launch_bounds__(256, 6) void backproject_kernel(const float* __restrict__ filt,
                                                             const float* __restrict__ ws,
                                                             float* __restrict__ out) {
    __shared__ __attribute__((aligned(16))) float2 win[2][4][WREG];   // 21 KB
    __shared__ float cstbuf[2][WCHUNK];

    const int tid  = threadIdx.x;
    const int bidx = (int)blockIdx.x;
    const int sixth = bidx >> 8;           // 0..5: angle range
    const int rem  = bidx & 255;
    const int b    = (rem >> 6) * 8;       // batches b .. b+7
    const int tile = rem & 63;             // 8 x 8 tiles of 32x32
    const int i0 = (tile >> 3) * 32;
    const int j0 = (tile & 7) * 32;

    const float* trig = ws + 512;

    // compute-phase pixel mapping: wave = 16x16 px, lane = 2x2 px patch
    const int w  = tid >> 6;
    const int l  = tid & 63;
    const int wi = (w >> 1) * 16, wj = (w & 1) * 16;
    const int li = l >> 3, lj = l & 7;
    const int pi = i0 + wi + 2 * li;
    const int pj = j0 + wj + 2 * lj;
    const float xi = -1.f + ((float)pi + 0.5f) * DX_F;
    const float yj = -1.f + ((float)pj + 0.5f) * DX_F;

    // staging mapping: wave sa stages angle sa; sg = batch-pair; st segment
    const int sa = tid >> 6;               // 0..3 (wave-coherent)
    const int sg = (tid >> 4) & 3;         // batch-pair 0..3
    const int st = tid & 15;               // segment, <14 active
    const bool sact = (st < 14);
    const float xlo = -1.f + ((float)i0 + 0.5f) * DX_F;
    const float xhi = xlo + 31.f * DX_F;
    const float ylo = -1.f + ((float)j0 + 0.5f) * DX_F;
    const float yhi = ylo + 31.f * DX_F;

    const float* fb0 = filt + (size_t)b * (NPHI * FSTR);

    float acc[8][2][2];
    #pragma unroll
    for (int bb = 0; bb < 8; ++bb)
        #pragma unroll
        for (int di = 0; di < 2; ++di)
            #pragma unroll
            for (int dj = 0; dj < 2; ++dj) acc[bb][di][dj] = 0.f;

    // staging state (landing registers): one batch-pair = 2 streams x 6 f32
    float fA[6], fB[6];
    float b0reg = 0.f;
    int   s0reg = 0;

    auto LOADREGS = [&](int p0c) {
        if (!sact) return;
        const int p = p0c + sa;
        const float4 tg = *(const float4*)&trig[p * 4];
        const float umin = 256.5f + fminf(xlo * tg.x, xhi * tg.x)
                                  + fminf(ylo * tg.y, yhi * tg.y);
        const float b0f = floorf(umin) - 1.f;
        b0reg = b0f;
        const int b0 = (int)b0f;
        const int base  = b0 + 5 * st - 1;
        const int basec = min(base, 506);
        s0reg = sa * WSTR + (basec - b0 + 1);
        const float* rA = fb0 + (size_t)(2 * sg) * (NPHI * FSTR)
                              + (size_t)p * FSTR + 4 + basec;
        const float* rB = rA + (size_t)(NPHI * FSTR);
        f32x4u a0 = *(const f32x4u*)rA;
        f32x2u a1 = *(const f32x2u*)(rA + 4);
        f32x4u c0 = *(const f32x4u*)rB;
        f32x2u c1 = *(const f32x2u*)(rB + 4);
        fA[0] = a0[0]; fA[1] = a0[1]; fA[2] = a0[2];
        fA[3] = a0[3]; fA[4] = a1[0]; fA[5] = a1[1];
        fB[0] = c0[0]; fB[1] = c0[1]; fB[2] = c0[2];
        fB[3] = c0[3]; fB[4] = c1[0]; fB[5] = c1[1];
    };

    auto WRITE_LDS = [&](int bf) {
        if (!sact) return;
        if ((tid & 63) == 0) cstbuf[bf][sa] = 256.5f - b0reg;
        #pragma unroll
        for (int j = 0; j < 5; ++j) {
            h2 pa = __builtin_amdgcn_cvt_pkrtz(fA[j], fA[j + 1]);
            h2 pb = __builtin_amdgcn_cvt_pkrtz(fB[j], fB[j + 1]);
            win[bf][sg][s0reg + j] = make_float2(__builtin_bit_cast(float, pa),
                                                 __builtin_bit_cast(float, pb));
        }
    };

    const int pbeg = sixth * 120;
    LOADREGS(pbeg);
    WRITE_LDS(0);
    __syncthreads();

    for (int c = 0; c < 30; ++c) {
        const int cur = c & 1;
        if (c + 1 < 30) LOADREGS(pbeg + (c + 1) * WCHUNK);   // issue early

        const int p0 = pbeg + c * WCHUNK;
        #pragma unroll
        for (int a = 0; a < WCHUNK; ++a) {
            const float4 tg = *(const float4*)&trig[(p0 + a) * 4]; // cd,sd,dci,dsj
            const float cst = cstbuf[cur][a];
            const float2* wr = &win[cur][0][a * WSTR];
            const float u00 = xi * tg.x + yj * tg.y + cst;
            #pragma unroll
            for (int di = 0; di < 2; ++di) {
                float u = di ? (u00 + tg.z) : u00;
                #pragma unroll
                for (int dj = 0; dj < 2; ++dj) {
                    float fl = floorf(u);
                    float wv = u - fl;
                    int  ip  = (int)fl;
                    h2   wp  = __builtin_amdgcn_cvt_pkrtz(1.f - wv, wv);
                    float2 s01 = wr[ip];
                    float2 s23 = wr[ip + WREG];
                    float2 s45 = wr[ip + 2 * WREG];
                    float2 s67 = wr[ip + 3 * WREG];
                    acc[0][di][dj] = fdot2f(wp, s01.x, acc[0][di][dj]);
                    acc[1][di][dj] = fdot2f(wp, s01.y, acc[1][di][dj]);
                    acc[2][di][dj] = fdot2f(wp, s23.x, acc[2][di][dj]);
                    acc[3][di][dj] = fdot2f(wp, s23.y, acc[3][di][dj]);
                    acc[4][di][dj] = fdot2f(wp, s45.x, acc[4][di][dj]);
                    acc[5][di][dj] = fdot2f(wp, s45.y, acc[5][di][dj]);
                    acc[6][di][dj] = fdot2f(wp, s67.x, acc[6][di][dj]);
                    acc[7][di][dj] = fdot2f(wp, s67.y, acc[7][di][dj]);
                    u += tg.w;
                }
            }
        }

        if (c + 1 < 30) WRITE_LDS((c + 1) & 1);              // overlaps compute
        __syncthreads();
    }

    #pragma unroll
    for (int bb = 0; bb < 8; ++bb) {
        float* ob = out + (size_t)(b + bb) * (NH * NH) + (size_t)pi * NH + pj;
        #pragma unroll
        for (int di = 0; di < 2; ++di)
            #pragma unroll
            for (int dj = 0; dj < 2; ++dj)
                unsafeAtomicAdd(ob + di * NH + dj, acc[bb][di][dj] * DPHI_F);
    }
}

// ---------------------------------------------------------------------------
extern "C" void kernel_launch(void* const* d_in, const int* in_sizes, int n_in,
                              void* d_out, int out_size, void* d_ws, size_t ws_size,
                              hipStream_t stream) {
    const float* sinos = (const float*)d_in[0];   // [32,720,512] f32
    const float* kern  = (const float*)d_in[1];   // [257] f32
    float* out = (float*)d_out;                   // [32,256,256] f32
    float* ws  = (float*)d_ws;

    // ws layout: [0,4096) f32 tables; then padded filt f32 (23040x520 = 47.9MB)
    float* filt = ws + 4096;

    hipLaunchKernelGGL(front_kernel, dim3(490), dim3(512), 0, stream,
                       sinos, kern, ws, (float4*)out, filt);
    hipLaunchKernelGGL(backproject_kernel, dim3(6 * (NB / 8) * 64), dim3(256), 0, stream,
                       filt, ws, out);
}

// Round 19
// 192.602 us; speedup vs baseline: 13.9243x; 13.9243x over previous
//
#include <hip/hip_runtime.h>
#include <hip/hip_bf16.h>

// Geometry constants
#define NPHI 720
#define NT   512
#define NH   256
#define NB   32

#define DPHI_F   0.004363323129985824f   // pi/720
#define INV_DT_F 181.01933598375618f     // 256/sqrt(2)
#define DX_F     0.0078125f              // 2/256
#define W2PI_F   0.012271846303085130f   // 2*pi/512

#define FSTR 520   // padded filt row stride (4 zero | 512 data | 4 zero)

typedef __fp16  h2   __attribute__((ext_vector_type(2)));   // cvt_pkrtz return type
typedef _Float16 f16x2 __attribute__((ext_vector_type(2))); // fdot2 operand type
typedef _Float16 f16x8 __attribute__((ext_vector_type(8))); // mfma A/B operand
typedef float    f32x4 __attribute__((ext_vector_type(4))); // mfma C/D
typedef float    f32x4u __attribute__((ext_vector_type(4), aligned(4)));
typedef float    f32x2u __attribute__((ext_vector_type(2), aligned(4)));

__device__ __forceinline__ float fdot2f(h2 a, float b_bits, float c) {
    return __builtin_amdgcn_fdot2(__builtin_bit_cast(f16x2, a),
                                  __builtin_bit_cast(f16x2, b_bits), c, false);
}

// ---------------------------------------------------------------------------
// Front kernel (R16-measured, verbatim): GEMM filtering + all setup.
//  blocks [0,360):   GEMM 64(M) x 512(N) x 32(K), circulant B built ONCE in
//                    LDS from locally-computed h; A staged per k-step.
//  blocks [360,362): trig table   [362,426): zero out   [426,490): zero pads
// ---------------------------------------------------------------------------
#define ASTR 40
#define BSTR 40

__global__ __launch_bounds__(512) void front_kernel(const float* __restrict__ g,
                                                    const float* __restrict__ kern,
                                                    float* __restrict__ ws,
                                                    float4* __restrict__ out4,
                                                    float* __restrict__ filt) {
    __shared__ __attribute__((aligned(16))) unsigned short As[64 * ASTR];   // 5.12 KB
    __shared__ __attribute__((aligned(16))) unsigned short Bs[512 * BSTR];  // 40 KB
    __shared__ float hloc[512];
    const int bid = (int)blockIdx.x;
    const int tid = threadIdx.x;

    if (bid < 360) {
        // ---- prologue: h = irfft(K,512), then circulant Bs (once) ----
        float* ctab = (float*)As;        // 2 KB alias, dead after prologue
        float* kkp  = (float*)Bs;        // 1 KB alias, dead after prologue
        if (tid < 257) kkp[tid] = kern[tid];
        ctab[tid] = cosf((float)tid * W2PI_F);
        __syncthreads();
        {
            float acc = 0.f;
            for (int k = 1; k < 256; ++k)
                acc += kkp[k] * ctab[(k * tid) & 511];
            hloc[tid] = (kkp[0] + ((tid & 1) ? -kkp[256] : kkp[256]) + 2.f * acc)
                        * (1.f / 512.f);
        }
        __syncthreads();
        {   // Bs row d = tid: Bs[d][m] = h[(d-m)&511], packed fp16 pairs
            unsigned int uu[16];
            #pragma unroll
            for (int q = 0; q < 16; ++q) {
                float lo = hloc[(tid - 2 * q) & 511];
                float hi = hloc[(tid - 2 * q - 1) & 511];
                h2 p = __builtin_amdgcn_cvt_pkrtz(lo, hi);
                uu[q] = __builtin_bit_cast(unsigned int, p);
            }
            unsigned int* dst = (unsigned int*)&Bs[tid * BSTR];
            *(uint4*)(dst)      = make_uint4(uu[0], uu[1], uu[2], uu[3]);
            *(uint4*)(dst + 4)  = make_uint4(uu[4], uu[5], uu[6], uu[7]);
            *(uint4*)(dst + 8)  = make_uint4(uu[8], uu[9], uu[10], uu[11]);
            *(uint4*)(dst + 12) = make_uint4(uu[12], uu[13], uu[14], uu[15]);
        }

        // ---- GEMM ----
        const int m0 = bid * 64;
        const int w = tid >> 6, l = tid & 63;
        const int wm = (w >> 2) * 32;          // 0 or 32
        const int wn = (w & 3) * 128;          // 0,128,256,384
        const int fr = l & 15, g16 = l >> 4;
        const int arow = tid >> 3, aq = (tid & 7) * 4;

        f32x4 acc[2][8];
        #pragma unroll
        for (int i = 0; i < 2; ++i)
            #pragma unroll
            for (int j = 0; j < 8; ++j) acc[i][j] = (f32x4){0.f, 0.f, 0.f, 0.f};

        for (int k0 = 0; k0 < 512; k0 += 32) {
            __syncthreads();
            {   // stage A: 64 rows x 32 fp16
                const float* src = g + (size_t)(m0 + arow) * NT + (k0 + aq);
                float4 v = *(const float4*)src;
                h2 p0 = __builtin_amdgcn_cvt_pkrtz(v.x, v.y);
                h2 p1 = __builtin_amdgcn_cvt_pkrtz(v.z, v.w);
                *(uint2*)&As[arow * ASTR + aq] =
                    make_uint2(__builtin_bit_cast(unsigned int, p0),
                               __builtin_bit_cast(unsigned int, p1));
            }
            __syncthreads();

            f16x8 af[2], bf[8];
            #pragma unroll
            for (int i = 0; i < 2; ++i)
                af[i] = *(const f16x8*)&As[(wm + i * 16 + fr) * ASTR + g16 * 8];
            const int rbase = (wn + fr - k0) & 511;
            #pragma unroll
            for (int j = 0; j < 8; ++j) {
                const int row = (rbase + j * 16) & 511;
                bf[j] = *(const f16x8*)&Bs[row * BSTR + g16 * 8];
            }
            #pragma unroll
            for (int i = 0; i < 2; ++i)
                #pragma unroll
                for (int j = 0; j < 8; ++j)
                    acc[i][j] = __builtin_amdgcn_mfma_f32_16x16x32_f16(af[i], bf[j], acc[i][j], 0, 0, 0);
        }

        #pragma unroll
        for (int i = 0; i < 2; ++i)
            #pragma unroll
            for (int j = 0; j < 8; ++j)
                #pragma unroll
                for (int v = 0; v < 4; ++v) {
                    int row = m0 + wm + i * 16 + g16 * 4 + v;
                    int col = wn + j * 16 + fr;
                    filt[(size_t)row * FSTR + 4 + col] = acc[i][j][v];
                }
    } else if (bid < 362) {
        int p = (bid - 360) * 512 + tid;
        if (p < NPHI) {
            float ang = ((float)p + 0.5f) * DPHI_F;
            float s, c;
            sincosf(ang, &s, &c);
            float cd = c * INV_DT_F;
            float sd = s * INV_DT_F;
            ws[512 + 4 * p + 0] = cd;
            ws[512 + 4 * p + 1] = sd;
            ws[512 + 4 * p + 2] = cd * DX_F;
            ws[512 + 4 * p + 3] = sd * DX_F;
        }
    } else if (bid < 426) {
        const float4 z = make_float4(0.f, 0.f, 0.f, 0.f);
        const int nout4 = NB * NH * NH / 4;            // 524288
        for (int i = (bid - 362) * 512 + tid; i < nout4; i += 64 * 512)
            out4[i] = z;
    } else {
        const float4 z = make_float4(0.f, 0.f, 0.f, 0.f);
        const int nslots = 23040 * 2;                  // 46080
        for (int i = (bid - 426) * 512 + tid; i < nslots; i += 64 * 512) {
            int row = i >> 1;
            float* p = filt + (size_t)row * FSTR + ((i & 1) ? 516 : 0);
            *(float4*)p = z;
        }
    }
}

// ---------------------------------------------------------------------------
// Kernel C: backprojection v12b -- ping-pong win buffer, pressure-controlled.
// [R18 post-mortem: launch_bounds(256,6) + full unroll forced acc spill to
//  scratch (FETCH 3.6GB, 17x slowdown). Fix: bounds (256,4) = 128-VGPR
//  budget, unroll 2 on angle loop (R17's proven depth). LDS 21KB still
//  allows ~7 blocks/CU; natural VGPR ~70-80 keeps 6-7 waves/SIMD.]
// Grid = 6 angle-sixths x 4 batch-octs x 64 tiles = 1536 blocks.
// WCHUNK=4 (30 sub-chunks).  Pipeline per sub-chunk: LOADREGS(c+1) issue ->
// COMPUTE(buf[c&1]) -> WRITE_LDS(buf[(c+1)&1]) (overlaps other waves'
// compute; vmcnt wait hidden by compute) -> ONE barrier.
// Staging: wave-coherent -- sa=tid>>6 (wave=angle), sg=(tid>>4)&3
// (batch-pair), st=tid&15 (<14).  12 landing f32/thread.
// Index convention (R1/R3/R4-verified): ip = floor(q + cst), cst = 256.5-b0.
// ---------------------------------------------------------------------------
#define WCHUNK 4
#define WSTR   82
#define WREG   (WCHUNK * WSTR)    // 328 float2 per region per buffer

__global__ __launch_bounds__(256, 4) void backproject_kernel(const float* __restrict__ filt,
                                                             const float* __restrict__ ws,
                                                             float* __restrict__ out) {
    __shared__ __attribute__((aligned(16))) float2 win[2][4][WREG];   // 21 KB
    __shared__ float cstbuf[2][WCHUNK];

    const int tid  = threadIdx.x;
    const int bidx = (int)blockIdx.x;
    const int sixth = bidx >> 8;           // 0..5: angle range
    const int rem  = bidx & 255;
    const int b    = (rem >> 6) * 8;       // batches b .. b+7
    const int tile = rem & 63;             // 8 x 8 tiles of 32x32
    const int i0 = (tile >> 3) * 32;
    const int j0 = (tile & 7) * 32;

    const float* trig = ws + 512;

    // compute-phase pixel mapping: wave = 16x16 px, lane = 2x2 px patch
    const int w  = tid >> 6;
    const int l  = tid & 63;
    const int wi = (w >> 1) * 16, wj = (w & 1) * 16;
    const int li = l >> 3, lj = l & 7;
    const int pi = i0 + wi + 2 * li;
    const int pj = j0 + wj + 2 * lj;
    const float xi = -1.f + ((float)pi + 0.5f) * DX_F;
    const float yj = -1.f + ((float)pj + 0.5f) * DX_F;

    // staging mapping: wave sa stages angle sa; sg = batch-pair; st segment
    const int sa = tid >> 6;               // 0..3 (wave-coherent)
    const int sg = (tid >> 4) & 3;         // batch-pair 0..3
    const int st = tid & 15;               // segment, <14 active
    const bool sact = (st < 14);
    const float xlo = -1.f + ((float)i0 + 0.5f) * DX_F;
    const float xhi = xlo + 31.f * DX_F;
    const float ylo = -1.f + ((float)j0 + 0.5f) * DX_F;
    const float yhi = ylo + 31.f * DX_F;

    const float* fb0 = filt + (size_t)b * (NPHI * FSTR);

    float acc[8][2][2];
    #pragma unroll
    for (int bb = 0; bb < 8; ++bb)
        #pragma unroll
        for (int di = 0; di < 2; ++di)
            #pragma unroll
            for (int dj = 0; dj < 2; ++dj) acc[bb][di][dj] = 0.f;

    // staging state (landing registers): one batch-pair = 2 streams x 6 f32
    float fA[6], fB[6];
    float b0reg = 0.f;
    int   s0reg = 0;

    auto LOADREGS = [&](int p0c) {
        if (!sact) return;
        const int p = p0c + sa;
        const float4 tg = *(const float4*)&trig[p * 4];
        const float umin = 256.5f + fminf(xlo * tg.x, xhi * tg.x)
                                  + fminf(ylo * tg.y, yhi * tg.y);
        const float b0f = floorf(umin) - 1.f;
        b0reg = b0f;
        const int b0 = (int)b0f;
        const int base  = b0 + 5 * st - 1;
        const int basec = min(base, 506);
        s0reg = sa * WSTR + (basec - b0 + 1);
        const float* rA = fb0 + (size_t)(2 * sg) * (NPHI * FSTR)
                              + (size_t)p * FSTR + 4 + basec;
        const float* rB = rA + (size_t)(NPHI * FSTR);
        f32x4u a0 = *(const f32x4u*)rA;
        f32x2u a1 = *(const f32x2u*)(rA + 4);
        f32x4u c0 = *(const f32x4u*)rB;
        f32x2u c1 = *(const f32x2u*)(rB + 4);
        fA[0] = a0[0]; fA[1] = a0[1]; fA[2] = a0[2];
        fA[3] = a0[3]; fA[4] = a1[0]; fA[5] = a1[1];
        fB[0] = c0[0]; fB[1] = c0[1]; fB[2] = c0[2];
        fB[3] = c0[3]; fB[4] = c1[0]; fB[5] = c1[1];
    };

    auto WRITE_LDS = [&](int bf) {
        if (!sact) return;
        if ((tid & 63) == 0) cstbuf[bf][sa] = 256.5f - b0reg;
        #pragma unroll
        for (int j = 0; j < 5; ++j) {
            h2 pa = __builtin_amdgcn_cvt_pkrtz(fA[j], fA[j + 1]);
            h2 pb = __builtin_amdgcn_cvt_pkrtz(fB[j], fB[j + 1]);
            win[bf][sg][s0reg + j] = make_float2(__builtin_bit_cast(float, pa),
                                                 __builtin_bit_cast(float, pb));
        }
    };

    const int pbeg = sixth * 120;
    LOADREGS(pbeg);
    WRITE_LDS(0);
    __syncthreads();

    for (int c = 0; c < 30; ++c) {
        const int cur = c & 1;
        if (c + 1 < 30) LOADREGS(pbeg + (c + 1) * WCHUNK);   // issue early

        const int p0 = pbeg + c * WCHUNK;
        #pragma unroll 2
        for (int a = 0; a < WCHUNK; ++a) {
            const float4 tg = *(const float4*)&trig[(p0 + a) * 4]; // cd,sd,dci,dsj
            const float cst = cstbuf[cur][a];
            const float2* wr = &win[cur][0][a * WSTR];
            const float u00 = xi * tg.x + yj * tg.y + cst;
            #pragma unroll
            for (int di = 0; di < 2; ++di) {
                float u = di ? (u00 + tg.z) : u00;
                #pragma unroll
                for (int dj = 0; dj < 2; ++dj) {
                    float fl = floorf(u);
                    float wv = u - fl;
                    int  ip  = (int)fl;
                    h2   wp  = __builtin_amdgcn_cvt_pkrtz(1.f - wv, wv);
                    float2 s01 = wr[ip];
                    float2 s23 = wr[ip + WREG];
                    float2 s45 = wr[ip + 2 * WREG];
                    float2 s67 = wr[ip + 3 * WREG];
                    acc[0][di][dj] = fdot2f(wp, s01.x, acc[0][di][dj]);
                    acc[1][di][dj] = fdot2f(wp, s01.y, acc[1][di][dj]);
                    acc[2][di][dj] = fdot2f(wp, s23.x, acc[2][di][dj]);
                    acc[3][di][dj] = fdot2f(wp, s23.y, acc[3][di][dj]);
                    acc[4][di][dj] = fdot2f(wp, s45.x, acc[4][di][dj]);
                    acc[5][di][dj] = fdot2f(wp, s45.y, acc[5][di][dj]);
                    acc[6][di][dj] = fdot2f(wp, s67.x, acc[6][di][dj]);
                    acc[7][di][dj] = fdot2f(wp, s67.y, acc[7][di][dj]);
                    u += tg.w;
                }
            }
        }

        if (c + 1 < 30) WRITE_LDS((c + 1) & 1);              // overlaps compute
        __syncthreads();
    }

    #pragma unroll
    for (int bb = 0; bb < 8; ++bb) {
        float* ob = out + (size_t)(b + bb) * (NH * NH) + (size_t)pi * NH + pj;
        #pragma unroll
        for (int di = 0; di < 2; ++di)
            #pragma unroll
            for (int dj = 0; dj < 2; ++dj)
                unsafeAtomicAdd(ob + di * NH + dj, acc[bb][di][dj] * DPHI_F);
    }
}

// ---------------------------------------------------------------------------
extern "C" void kernel_launch(void* const* d_in, const int* in_sizes, int n_in,
                              void* d_out, int out_size, void* d_ws, size_t ws_size,
                              hipStream_t stream) {
    const float* sinos = (const float*)d_in[0];   // [32,720,512] f32
    const float* kern  = (const float*)d_in[1];   // [257] f32
    float* out = (float*)d_out;                   // [32,256,256] f32
    float* ws  = (float*)d_ws;

    // ws layout: [0,4096) f32 tables; then padded filt f32 (23040x520 = 47.9MB)
    float* filt = ws + 4096;

    hipLaunchKernelGGL(front_kernel, dim3(490), dim3(512), 0, stream,
                       sinos, kern, ws, (float4*)out, filt);
    hipLaunchKernelGGL(backproject_kernel, dim3(6 * (NB / 8) * 64), dim3(256), 0, stream,
                       filt, ws, out);
}

// Round 20
// 192.151 us; speedup vs baseline: 13.9570x; 1.0023x over previous
//
#include <hip/hip_runtime.h>
#include <hip/hip_bf16.h>

// Geometry constants
#define NPHI 720
#define NT   512
#define NH   256
#define NB   32

#define DPHI_F   0.004363323129985824f   // pi/720
#define INV_DT_F 181.01933598375618f     // 256/sqrt(2)
#define DX_F     0.0078125f              // 2/256
#define W2PI_F   0.012271846303085130f   // 2*pi/512

#define FSTR 520   // padded filt row stride (4 zero | 512 data | 4 zero)

typedef __fp16  h2   __attribute__((ext_vector_type(2)));   // cvt_pkrtz return type
typedef _Float16 f16x2 __attribute__((ext_vector_type(2))); // fdot2 operand type
typedef _Float16 f16x8 __attribute__((ext_vector_type(8))); // mfma A/B operand
typedef float    f32x4 __attribute__((ext_vector_type(4))); // mfma C/D
typedef float    f32x4u __attribute__((ext_vector_type(4), aligned(4)));
typedef float    f32x2u __attribute__((ext_vector_type(2), aligned(4)));

__device__ __forceinline__ float fdot2f(h2 a, float b_bits, float c) {
    return __builtin_amdgcn_fdot2(__builtin_bit_cast(f16x2, a),
                                  __builtin_bit_cast(f16x2, b_bits), c, false);
}

// ---------------------------------------------------------------------------
// Front kernel (R16-measured, verbatim): GEMM filtering + all setup.
//  blocks [0,360):   GEMM 64(M) x 512(N) x 32(K), circulant B built ONCE in
//                    LDS from locally-computed h; A staged per k-step.
//  blocks [360,362): trig table   [362,426): zero out   [426,490): zero pads
// ---------------------------------------------------------------------------
#define ASTR 40
#define BSTR 40

__global__ __launch_bounds__(512) void front_kernel(const float* __restrict__ g,
                                                    const float* __restrict__ kern,
                                                    float* __restrict__ ws,
                                                    float4* __restrict__ out4,
                                                    float* __restrict__ filt) {
    __shared__ __attribute__((aligned(16))) unsigned short As[64 * ASTR];   // 5.12 KB
    __shared__ __attribute__((aligned(16))) unsigned short Bs[512 * BSTR];  // 40 KB
    __shared__ float hloc[512];
    const int bid = (int)blockIdx.x;
    const int tid = threadIdx.x;

    if (bid < 360) {
        // ---- prologue: h = irfft(K,512), then circulant Bs (once) ----
        float* ctab = (float*)As;        // 2 KB alias, dead after prologue
        float* kkp  = (float*)Bs;        // 1 KB alias, dead after prologue
        if (tid < 257) kkp[tid] = kern[tid];
        ctab[tid] = cosf((float)tid * W2PI_F);
        __syncthreads();
        {
            float acc = 0.f;
            for (int k = 1; k < 256; ++k)
                acc += kkp[k] * ctab[(k * tid) & 511];
            hloc[tid] = (kkp[0] + ((tid & 1) ? -kkp[256] : kkp[256]) + 2.f * acc)
                        * (1.f / 512.f);
        }
        __syncthreads();
        {   // Bs row d = tid: Bs[d][m] = h[(d-m)&511], packed fp16 pairs
            unsigned int uu[16];
            #pragma unroll
            for (int q = 0; q < 16; ++q) {
                float lo = hloc[(tid - 2 * q) & 511];
                float hi = hloc[(tid - 2 * q - 1) & 511];
                h2 p = __builtin_amdgcn_cvt_pkrtz(lo, hi);
                uu[q] = __builtin_bit_cast(unsigned int, p);
            }
            unsigned int* dst = (unsigned int*)&Bs[tid * BSTR];
            *(uint4*)(dst)      = make_uint4(uu[0], uu[1], uu[2], uu[3]);
            *(uint4*)(dst + 4)  = make_uint4(uu[4], uu[5], uu[6], uu[7]);
            *(uint4*)(dst + 8)  = make_uint4(uu[8], uu[9], uu[10], uu[11]);
            *(uint4*)(dst + 12) = make_uint4(uu[12], uu[13], uu[14], uu[15]);
        }

        // ---- GEMM ----
        const int m0 = bid * 64;
        const int w = tid >> 6, l = tid & 63;
        const int wm = (w >> 2) * 32;          // 0 or 32
        const int wn = (w & 3) * 128;          // 0,128,256,384
        const int fr = l & 15, g16 = l >> 4;
        const int arow = tid >> 3, aq = (tid & 7) * 4;

        f32x4 acc[2][8];
        #pragma unroll
        for (int i = 0; i < 2; ++i)
            #pragma unroll
            for (int j = 0; j < 8; ++j) acc[i][j] = (f32x4){0.f, 0.f, 0.f, 0.f};

        for (int k0 = 0; k0 < 512; k0 += 32) {
            __syncthreads();
            {   // stage A: 64 rows x 32 fp16
                const float* src = g + (size_t)(m0 + arow) * NT + (k0 + aq);
                float4 v = *(const float4*)src;
                h2 p0 = __builtin_amdgcn_cvt_pkrtz(v.x, v.y);
                h2 p1 = __builtin_amdgcn_cvt_pkrtz(v.z, v.w);
                *(uint2*)&As[arow * ASTR + aq] =
                    make_uint2(__builtin_bit_cast(unsigned int, p0),
                               __builtin_bit_cast(unsigned int, p1));
            }
            __syncthreads();

            f16x8 af[2], bf[8];
            #pragma unroll
            for (int i = 0; i < 2; ++i)
                af[i] = *(const f16x8*)&As[(wm + i * 16 + fr) * ASTR + g16 * 8];
            const int rbase = (wn + fr - k0) & 511;
            #pragma unroll
            for (int j = 0; j < 8; ++j) {
                const int row = (rbase + j * 16) & 511;
                bf[j] = *(const f16x8*)&Bs[row * BSTR + g16 * 8];
            }
            #pragma unroll
            for (int i = 0; i < 2; ++i)
                #pragma unroll
                for (int j = 0; j < 8; ++j)
                    acc[i][j] = __builtin_amdgcn_mfma_f32_16x16x32_f16(af[i], bf[j], acc[i][j], 0, 0, 0);
        }

        #pragma unroll
        for (int i = 0; i < 2; ++i)
            #pragma unroll
            for (int j = 0; j < 8; ++j)
                #pragma unroll
                for (int v = 0; v < 4; ++v) {
                    int row = m0 + wm + i * 16 + g16 * 4 + v;
                    int col = wn + j * 16 + fr;
                    filt[(size_t)row * FSTR + 4 + col] = acc[i][j][v];
                }
    } else if (bid < 362) {
        int p = (bid - 360) * 512 + tid;
        if (p < NPHI) {
            float ang = ((float)p + 0.5f) * DPHI_F;
            float s, c;
            sincosf(ang, &s, &c);
            float cd = c * INV_DT_F;
            float sd = s * INV_DT_F;
            ws[512 + 4 * p + 0] = cd;
            ws[512 + 4 * p + 1] = sd;
            ws[512 + 4 * p + 2] = cd * DX_F;
            ws[512 + 4 * p + 3] = sd * DX_F;
        }
    } else if (bid < 426) {
        const float4 z = make_float4(0.f, 0.f, 0.f, 0.f);
        const int nout4 = NB * NH * NH / 4;            // 524288
        for (int i = (bid - 362) * 512 + tid; i < nout4; i += 64 * 512)
            out4[i] = z;
    } else {
        const float4 z = make_float4(0.f, 0.f, 0.f, 0.f);
        const int nslots = 23040 * 2;                  // 46080
        for (int i = (bid - 426) * 512 + tid; i < nslots; i += 64 * 512) {
            int row = i >> 1;
            float* p = filt + (size_t)row * FSTR + ((i & 1) ? 516 : 0);
            *(float4*)p = z;
        }
    }
}

// ---------------------------------------------------------------------------
// Kernel C: backprojection v12c -- ping-pong win buffer at 6 blocks/CU.
// [R18: (256,6)+full-unroll spilled (FETCH 3.6GB). R19: (256,4)+unroll2
//  fixed spill (VGPR 60) but halved residency (occ 34%, BP 166 > R17 157).
//  R20: unroll2 body measured at 60 VGPR fits (256,6)'s ~85 budget ->
//  6 blocks/CU with no spill. Single variable vs R19.]
// Grid = 6 angle-sixths x 4 batch-octs x 64 tiles = 1536 blocks.
// WCHUNK=4 (30 sub-chunks).  Pipeline per sub-chunk: LOADREGS(c+1) issue ->
// COMPUTE(buf[c&1]) -> WRITE_LDS(buf[(c+1)&1]) (overlaps other waves'
// compute) -> ONE barrier.
// Staging: wave-coherent -- sa=tid>>6 (wave=angle), sg=(tid>>4)&3
// (batch-pair), st=tid&15 (<14).  12 landing f32/thread.
// Index convention (R1/R3/R4-verified): ip = floor(q + cst), cst = 256.5-b0.
// ---------------------------------------------------------------------------
#define WCHUNK 4
#define WSTR   82
#define WREG   (WCHUNK * WSTR)    // 328 float2 per region per buffer

__global__ __launch_bounds__(256, 6) void backproject_kernel(const float* __restrict__ filt,
                                                             const float* __restrict__ ws,
                                                             float* __restrict__ out) {
    __shared__ __attribute__((aligned(16))) float2 win[2][4][WREG];   // 21 KB
    __shared__ float cstbuf[2][WCHUNK];

    const int tid  = threadIdx.x;
    const int bidx = (int)blockIdx.x;
    const int sixth = bidx >> 8;           // 0..5: angle range
    const int rem  = bidx & 255;
    const int b    = (rem >> 6) * 8;       // batches b .. b+7
    const int tile = rem & 63;             // 8 x 8 tiles of 32x32
    const int i0 = (tile >> 3) * 32;
    const int j0 = (tile & 7) * 32;

    const float* trig = ws + 512;

    // compute-phase pixel mapping: wave = 16x16 px, lane = 2x2 px patch
    const int w  = tid >> 6;
    const int l  = tid & 63;
    const int wi = (w >> 1) * 16, wj = (w & 1) * 16;
    const int li = l >> 3, lj = l & 7;
    const int pi = i0 + wi + 2 * li;
    const int pj = j0 + wj + 2 * lj;
    const float xi = -1.f + ((float)pi + 0.5f) * DX_F;
    const float yj = -1.f + ((float)pj + 0.5f) * DX_F;

    // staging mapping: wave sa stages angle sa; sg = batch-pair; st segment
    const int sa = tid >> 6;               // 0..3 (wave-coherent)
    const int sg = (tid >> 4) & 3;         // batch-pair 0..3
    const int st = tid & 15;               // segment, <14 active
    const bool sact = (st < 14);
    const float xlo = -1.f + ((float)i0 + 0.5f) * DX_F;
    const float xhi = xlo + 31.f * DX_F;
    const float ylo = -1.f + ((float)j0 + 0.5f) * DX_F;
    const float yhi = ylo + 31.f * DX_F;

    const float* fb0 = filt + (size_t)b * (NPHI * FSTR);

    float acc[8][2][2];
    #pragma unroll
    for (int bb = 0; bb < 8; ++bb)
        #pragma unroll
        for (int di = 0; di < 2; ++di)
            #pragma unroll
            for (int dj = 0; dj < 2; ++dj) acc[bb][di][dj] = 0.f;

    // staging state (landing registers): one batch-pair = 2 streams x 6 f32
    float fA[6], fB[6];
    float b0reg = 0.f;
    int   s0reg = 0;

    auto LOADREGS = [&](int p0c) {
        if (!sact) return;
        const int p = p0c + sa;
        const float4 tg = *(const float4*)&trig[p * 4];
        const float umin = 256.5f + fminf(xlo * tg.x, xhi * tg.x)
                                  + fminf(ylo * tg.y, yhi * tg.y);
        const float b0f = floorf(umin) - 1.f;
        b0reg = b0f;
        const int b0 = (int)b0f;
        const int base  = b0 + 5 * st - 1;
        const int basec = min(base, 506);
        s0reg = sa * WSTR + (basec - b0 + 1);
        const float* rA = fb0 + (size_t)(2 * sg) * (NPHI * FSTR)
                              + (size_t)p * FSTR + 4 + basec;
        const float* rB = rA + (size_t)(NPHI * FSTR);
        f32x4u a0 = *(const f32x4u*)rA;
        f32x2u a1 = *(const f32x2u*)(rA + 4);
        f32x4u c0 = *(const f32x4u*)rB;
        f32x2u c1 = *(const f32x2u*)(rB + 4);
        fA[0] = a0[0]; fA[1] = a0[1]; fA[2] = a0[2];
        fA[3] = a0[3]; fA[4] = a1[0]; fA[5] = a1[1];
        fB[0] = c0[0]; fB[1] = c0[1]; fB[2] = c0[2];
        fB[3] = c0[3]; fB[4] = c1[0]; fB[5] = c1[1];
    };

    auto WRITE_LDS = [&](int bf) {
        if (!sact) return;
        if ((tid & 63) == 0) cstbuf[bf][sa] = 256.5f - b0reg;
        #pragma unroll
        for (int j = 0; j < 5; ++j) {
            h2 pa = __builtin_amdgcn_cvt_pkrtz(fA[j], fA[j + 1]);
            h2 pb = __builtin_amdgcn_cvt_pkrtz(fB[j], fB[j + 1]);
            win[bf][sg][s0reg + j] = make_float2(__builtin_bit_cast(float, pa),
                                                 __builtin_bit_cast(float, pb));
        }
    };

    const int pbeg = sixth * 120;
    LOADREGS(pbeg);
    WRITE_LDS(0);
    __syncthreads();

    for (int c = 0; c < 30; ++c) {
        const int cur = c & 1;
        if (c + 1 < 30) LOADREGS(pbeg + (c + 1) * WCHUNK);   // issue early

        const int p0 = pbeg + c * WCHUNK;
        #pragma unroll 2
        for (int a = 0; a < WCHUNK; ++a) {
            const float4 tg = *(const float4*)&trig[(p0 + a) * 4]; // cd,sd,dci,dsj
            const float cst = cstbuf[cur][a];
            const float2* wr = &win[cur][0][a * WSTR];
            const float u00 = xi * tg.x + yj * tg.y + cst;
            #pragma unroll
            for (int di = 0; di < 2; ++di) {
                float u = di ? (u00 + tg.z) : u00;
                #pragma unroll
                for (int dj = 0; dj < 2; ++dj) {
                    float fl = floorf(u);
                    float wv = u - fl;
                    int  ip  = (int)fl;
                    h2   wp  = __builtin_amdgcn_cvt_pkrtz(1.f - wv, wv);
                    float2 s01 = wr[ip];
                    float2 s23 = wr[ip + WREG];
                    float2 s45 = wr[ip + 2 * WREG];
                    float2 s67 = wr[ip + 3 * WREG];
                    acc[0][di][dj] = fdot2f(wp, s01.x, acc[0][di][dj]);
                    acc[1][di][dj] = fdot2f(wp, s01.y, acc[1][di][dj]);
                    acc[2][di][dj] = fdot2f(wp, s23.x, acc[2][di][dj]);
                    acc[3][di][dj] = fdot2f(wp, s23.y, acc[3][di][dj]);
                    acc[4][di][dj] = fdot2f(wp, s45.x, acc[4][di][dj]);
                    acc[5][di][dj] = fdot2f(wp, s45.y, acc[5][di][dj]);
                    acc[6][di][dj] = fdot2f(wp, s67.x, acc[6][di][dj]);
                    acc[7][di][dj] = fdot2f(wp, s67.y, acc[7][di][dj]);
                    u += tg.w;
                }
            }
        }

        if (c + 1 < 30) WRITE_LDS((c + 1) & 1);              // overlaps compute
        __syncthreads();
    }

    #pragma unroll
    for (int bb = 0; bb < 8; ++bb) {
        float* ob = out + (size_t)(b + bb) * (NH * NH) + (size_t)pi * NH + pj;
        #pragma unroll
        for (int di = 0; di < 2; ++di)
            #pragma unroll
            for (int dj = 0; dj < 2; ++dj)
                unsafeAtomicAdd(ob + di * NH + dj, acc[bb][di][dj] * DPHI_F);
    }
}

// ---------------------------------------------------------------------------
extern "C" void kernel_launch(void* const* d_in, const int* in_sizes, int n_in,
                              void* d_out, int out_size, void* d_ws, size_t ws_size,
                              hipStream_t stream) {
    const float* sinos = (const float*)d_in[0];   // [32,720,512] f32
    const float* kern  = (const float*)d_in[1];   // [257] f32
    float* out = (float*)d_out;                   // [32,256,256] f32
    float* ws  = (float*)d_ws;

    // ws layout: [0,4096) f32 tables; then padded filt f32 (23040x520 = 47.9MB)
    float* filt = ws + 4096;

    hipLaunchKernelGGL(front_kernel, dim3(490), dim3(512), 0, stream,
                       sinos, kern, ws, (float4*)out, filt);
    hipLaunchKernelGGL(backproject_kernel, dim3(6 * (NB / 8) * 64), dim3(256), 0, stream,
                       filt, ws, out);
}

// Round 21
// 183.434 us; speedup vs baseline: 14.6203x; 1.0475x over previous
//
#include <hip/hip_runtime.h>
#include <hip/hip_bf16.h>

// Geometry constants
#define NPHI 720
#define NT   512
#define NH   256
#define NB   32

#define DPHI_F   0.004363323129985824f   // pi/720
#define INV_DT_F 181.01933598375618f     // 256/sqrt(2)
#define DX_F     0.0078125f              // 2/256
#define W2PI_F   0.012271846303085130f   // 2*pi/512

#define FSTR 520   // padded filt row stride (4 zero | 512 data | 4 zero)

typedef __fp16  h2   __attribute__((ext_vector_type(2)));   // cvt_pkrtz return type
typedef _Float16 f16x2 __attribute__((ext_vector_type(2))); // fdot2 operand type
typedef _Float16 f16x8 __attribute__((ext_vector_type(8))); // mfma A/B operand
typedef float    f32x4 __attribute__((ext_vector_type(4))); // mfma C/D
typedef float    f32x4u __attribute__((ext_vector_type(4), aligned(4)));
typedef float    f32x2u __attribute__((ext_vector_type(2), aligned(4)));

__device__ __forceinline__ float fdot2f(h2 a, float b_bits, float c) {
    return __builtin_amdgcn_fdot2(__builtin_bit_cast(f16x2, a),
                                  __builtin_bit_cast(f16x2, b_bits), c, false);
}

// ---------------------------------------------------------------------------
// Front kernel (R16-measured, verbatim): GEMM filtering + all setup.
//  blocks [0,360):   GEMM 64(M) x 512(N) x 32(K), circulant B built ONCE in
//                    LDS from locally-computed h; A staged per k-step.
//  blocks [360,362): trig table   [362,426): zero out   [426,490): zero pads
// ---------------------------------------------------------------------------
#define ASTR 40
#define BSTR 40

__global__ __launch_bounds__(512) void front_kernel(const float* __restrict__ g,
                                                    const float* __restrict__ kern,
                                                    float* __restrict__ ws,
                                                    float4* __restrict__ out4,
                                                    float* __restrict__ filt) {
    __shared__ __attribute__((aligned(16))) unsigned short As[64 * ASTR];   // 5.12 KB
    __shared__ __attribute__((aligned(16))) unsigned short Bs[512 * BSTR];  // 40 KB
    __shared__ float hloc[512];
    const int bid = (int)blockIdx.x;
    const int tid = threadIdx.x;

    if (bid < 360) {
        // ---- prologue: h = irfft(K,512), then circulant Bs (once) ----
        float* ctab = (float*)As;        // 2 KB alias, dead after prologue
        float* kkp  = (float*)Bs;        // 1 KB alias, dead after prologue
        if (tid < 257) kkp[tid] = kern[tid];
        ctab[tid] = cosf((float)tid * W2PI_F);
        __syncthreads();
        {
            float acc = 0.f;
            for (int k = 1; k < 256; ++k)
                acc += kkp[k] * ctab[(k * tid) & 511];
            hloc[tid] = (kkp[0] + ((tid & 1) ? -kkp[256] : kkp[256]) + 2.f * acc)
                        * (1.f / 512.f);
        }
        __syncthreads();
        {   // Bs row d = tid: Bs[d][m] = h[(d-m)&511], packed fp16 pairs
            unsigned int uu[16];
            #pragma unroll
            for (int q = 0; q < 16; ++q) {
                float lo = hloc[(tid - 2 * q) & 511];
                float hi = hloc[(tid - 2 * q - 1) & 511];
                h2 p = __builtin_amdgcn_cvt_pkrtz(lo, hi);
                uu[q] = __builtin_bit_cast(unsigned int, p);
            }
            unsigned int* dst = (unsigned int*)&Bs[tid * BSTR];
            *(uint4*)(dst)      = make_uint4(uu[0], uu[1], uu[2], uu[3]);
            *(uint4*)(dst + 4)  = make_uint4(uu[4], uu[5], uu[6], uu[7]);
            *(uint4*)(dst + 8)  = make_uint4(uu[8], uu[9], uu[10], uu[11]);
            *(uint4*)(dst + 12) = make_uint4(uu[12], uu[13], uu[14], uu[15]);
        }

        // ---- GEMM ----
        const int m0 = bid * 64;
        const int w = tid >> 6, l = tid & 63;
        const int wm = (w >> 2) * 32;          // 0 or 32
        const int wn = (w & 3) * 128;          // 0,128,256,384
        const int fr = l & 15, g16 = l >> 4;
        const int arow = tid >> 3, aq = (tid & 7) * 4;

        f32x4 acc[2][8];
        #pragma unroll
        for (int i = 0; i < 2; ++i)
            #pragma unroll
            for (int j = 0; j < 8; ++j) acc[i][j] = (f32x4){0.f, 0.f, 0.f, 0.f};

        for (int k0 = 0; k0 < 512; k0 += 32) {
            __syncthreads();
            {   // stage A: 64 rows x 32 fp16
                const float* src = g + (size_t)(m0 + arow) * NT + (k0 + aq);
                float4 v = *(const float4*)src;
                h2 p0 = __builtin_amdgcn_cvt_pkrtz(v.x, v.y);
                h2 p1 = __builtin_amdgcn_cvt_pkrtz(v.z, v.w);
                *(uint2*)&As[arow * ASTR + aq] =
                    make_uint2(__builtin_bit_cast(unsigned int, p0),
                               __builtin_bit_cast(unsigned int, p1));
            }
            __syncthreads();

            f16x8 af[2], bf[8];
            #pragma unroll
            for (int i = 0; i < 2; ++i)
                af[i] = *(const f16x8*)&As[(wm + i * 16 + fr) * ASTR + g16 * 8];
            const int rbase = (wn + fr - k0) & 511;
            #pragma unroll
            for (int j = 0; j < 8; ++j) {
                const int row = (rbase + j * 16) & 511;
                bf[j] = *(const f16x8*)&Bs[row * BSTR + g16 * 8];
            }
            #pragma unroll
            for (int i = 0; i < 2; ++i)
                #pragma unroll
                for (int j = 0; j < 8; ++j)
                    acc[i][j] = __builtin_amdgcn_mfma_f32_16x16x32_f16(af[i], bf[j], acc[i][j], 0, 0, 0);
        }

        #pragma unroll
        for (int i = 0; i < 2; ++i)
            #pragma unroll
            for (int j = 0; j < 8; ++j)
                #pragma unroll
                for (int v = 0; v < 4; ++v) {
                    int row = m0 + wm + i * 16 + g16 * 4 + v;
                    int col = wn + j * 16 + fr;
                    filt[(size_t)row * FSTR + 4 + col] = acc[i][j][v];
                }
    } else if (bid < 362) {
        int p = (bid - 360) * 512 + tid;
        if (p < NPHI) {
            float ang = ((float)p + 0.5f) * DPHI_F;
            float s, c;
            sincosf(ang, &s, &c);
            float cd = c * INV_DT_F;
            float sd = s * INV_DT_F;
            ws[512 + 4 * p + 0] = cd;
            ws[512 + 4 * p + 1] = sd;
            ws[512 + 4 * p + 2] = cd * DX_F;
            ws[512 + 4 * p + 3] = sd * DX_F;
        }
    } else if (bid < 426) {
        const float4 z = make_float4(0.f, 0.f, 0.f, 0.f);
        const int nout4 = NB * NH * NH / 4;            // 524288
        for (int i = (bid - 362) * 512 + tid; i < nout4; i += 64 * 512)
            out4[i] = z;
    } else {
        const float4 z = make_float4(0.f, 0.f, 0.f, 0.f);
        const int nslots = 23040 * 2;                  // 46080
        for (int i = (bid - 426) * 512 + tid; i < nslots; i += 64 * 512) {
            int row = i >> 1;
            float* p = filt + (size_t)row * FSTR + ((i & 1) ? 516 : 0);
            *(float4*)p = z;
        }
    }
}

// ---------------------------------------------------------------------------
// Kernel C: backprojection v11 (R17-measured 156-157us, reverted verbatim).
// [R19/R20 post-mortem: single-barrier ping-pong (WCHUNK=4) tested at both
//  4 and 6 blocks/CU lands 161-166 -- worse than this two-barrier WCHUNK=8
//  structure. WCHUNK=4 halves the compute window hiding the prefetch.
//  BP structural floor: 4 B/sample through LDS = 115us pipe-busy; 157
//  = 1.36x with VALU 58% -- latency-bound local minimum, 3 restructures
//  failed to beat it. MFMA reformulation non-viable (2/96 sparsity).]
// Grid = 6 angle-sixths x 4 batch-octs x 64 tiles = 1536 blocks.
// WCHUNK=8; staging spread over ALL 256 threads: sa=tid>>5 (8 angles),
// sg=(tid>>4)&1 (batch half), st=tid&15 (<14 active) -> 24 landing
// f32/thread.  Loop: {barrier; WRITE_LDS(c); barrier; LOADREGS(c+1);
// COMPUTE(c)} -- global-load latency hides under compute.
// win[pp][a*WSTR+s] = {lo,hi of batch 2pp | 2pp+1} fp16 (8B); one address
// serves 4 ds_read_b64 (compile-time region offsets) = 8 samples.
// Index convention (R1/R3/R4-verified): ip = floor(q + cst), cst = 256.5-b0.
// ---------------------------------------------------------------------------
#define WCHUNK 8
#define WSTR   82
#define WREG   (WCHUNK * WSTR)

__global__ __launch_bounds__(256, 6) void backproject_kernel(const float* __restrict__ filt,
                                                             const float* __restrict__ ws,
                                                             float* __restrict__ out) {
    __shared__ __attribute__((aligned(16))) float2 win[4][WREG];   // 21 KB
    __shared__ float cstbuf[WCHUNK];

    const int tid  = threadIdx.x;
    const int bidx = (int)blockIdx.x;
    const int sixth = bidx >> 8;           // 0..5: angle range
    const int rem  = bidx & 255;
    const int b    = (rem >> 6) * 8;       // batches b .. b+7
    const int tile = rem & 63;             // 8 x 8 tiles of 32x32
    const int i0 = (tile >> 3) * 32;
    const int j0 = (tile & 7) * 32;

    const float* trig = ws + 512;

    // compute-phase pixel mapping: wave = 16x16 px, lane = 2x2 px patch
    const int w  = tid >> 6;
    const int l  = tid & 63;
    const int wi = (w >> 1) * 16, wj = (w & 1) * 16;
    const int li = l >> 3, lj = l & 7;
    const int pi = i0 + wi + 2 * li;
    const int pj = j0 + wj + 2 * lj;
    const float xi = -1.f + ((float)pi + 0.5f) * DX_F;
    const float yj = -1.f + ((float)pj + 0.5f) * DX_F;

    // staging mapping: 8 angles x 2 batch-halves x 14 threads
    const int sa = tid >> 5;               // angle in chunk
    const int sq = tid & 31;
    const int sg = sq >> 4;                // batch half
    const int st = sq & 15;                // segment, <14 active
    const bool sact = (st < 14);
    const float xlo = -1.f + ((float)i0 + 0.5f) * DX_F;
    const float xhi = xlo + 31.f * DX_F;
    const float ylo = -1.f + ((float)j0 + 0.5f) * DX_F;
    const float yhi = ylo + 31.f * DX_F;

    const float* fb0 = filt + (size_t)b * (NPHI * FSTR);

    float acc[8][2][2];
    #pragma unroll
    for (int bb = 0; bb < 8; ++bb)
        #pragma unroll
        for (int di = 0; di < 2; ++di)
            #pragma unroll
            for (int dj = 0; dj < 2; ++dj) acc[bb][di][dj] = 0.f;

    // staging state (landing registers)
    float fst[4][6];                       // streams: pr0A, pr0B, pr1A, pr1B
    float b0reg = 0.f;
    int   s0reg = 0;

    auto LOADREGS = [&](int p0c) {
        if (!sact) return;
        const int p = p0c + sa;
        const float4 tg = *(const float4*)&trig[p * 4];
        const float umin = 256.5f + fminf(xlo * tg.x, xhi * tg.x)
                                  + fminf(ylo * tg.y, yhi * tg.y);
        const float b0f = floorf(umin) - 1.f;
        b0reg = b0f;
        const int b0 = (int)b0f;
        const int base  = b0 + 5 * st - 1;
        const int basec = min(base, 506);
        s0reg = sa * WSTR + (basec - b0 + 1);
        #pragma unroll
        for (int pr = 0; pr < 2; ++pr) {
            const float* rA = fb0 + (size_t)(4 * sg + 2 * pr) * (NPHI * FSTR)
                                  + (size_t)p * FSTR + 4 + basec;
            const float* rB = rA + (size_t)(NPHI * FSTR);
            f32x4u a0 = *(const f32x4u*)rA;
            f32x2u a1 = *(const f32x2u*)(rA + 4);
            f32x4u c0 = *(const f32x4u*)rB;
            f32x2u c1 = *(const f32x2u*)(rB + 4);
            fst[2*pr+0][0] = a0[0]; fst[2*pr+0][1] = a0[1]; fst[2*pr+0][2] = a0[2];
            fst[2*pr+0][3] = a0[3]; fst[2*pr+0][4] = a1[0]; fst[2*pr+0][5] = a1[1];
            fst[2*pr+1][0] = c0[0]; fst[2*pr+1][1] = c0[1]; fst[2*pr+1][2] = c0[2];
            fst[2*pr+1][3] = c0[3]; fst[2*pr+1][4] = c1[0]; fst[2*pr+1][5] = c1[1];
        }
    };

    auto WRITE_LDS = [&]() {
        if (!sact) return;
        if (st == 0 && sg == 0) cstbuf[sa] = 256.5f - b0reg;
        #pragma unroll
        for (int pr = 0; pr < 2; ++pr) {
            #pragma unroll
            for (int j = 0; j < 5; ++j) {
                h2 pa = __builtin_amdgcn_cvt_pkrtz(fst[2*pr+0][j], fst[2*pr+0][j+1]);
                h2 pb = __builtin_amdgcn_cvt_pkrtz(fst[2*pr+1][j], fst[2*pr+1][j+1]);
                win[2 * sg + pr][s0reg + j] =
                    make_float2(__builtin_bit_cast(float, pa),
                                __builtin_bit_cast(float, pb));
            }
        }
    };

    const int pbeg = sixth * 120;
    LOADREGS(pbeg);
    for (int c = 0; c < 15; ++c) {
        __syncthreads();                   // win free (prev compute done)
        WRITE_LDS();
        __syncthreads();
        if (c + 1 < 15) LOADREGS(pbeg + (c + 1) * WCHUNK);   // issue early

        const int p0 = pbeg + c * WCHUNK;
        #pragma unroll 2
        for (int a = 0; a < WCHUNK; ++a) {
            const float4 tg = *(const float4*)&trig[(p0 + a) * 4]; // cd,sd,dci,dsj
            const float cst = cstbuf[a];
            const float2* wr = &win[0][a * WSTR];
            const float u00 = xi * tg.x + yj * tg.y + cst;
            #pragma unroll
            for (int di = 0; di < 2; ++di) {
                float u = di ? (u00 + tg.z) : u00;
                #pragma unroll
                for (int dj = 0; dj < 2; ++dj) {
                    float fl = floorf(u);
                    float wv = u - fl;
                    int  ip  = (int)fl;
                    h2   wp  = __builtin_amdgcn_cvt_pkrtz(1.f - wv, wv);
                    float2 s01 = wr[ip];
                    float2 s23 = wr[ip + WREG];
                    float2 s45 = wr[ip + 2 * WREG];
                    float2 s67 = wr[ip + 3 * WREG];
                    acc[0][di][dj] = fdot2f(wp, s01.x, acc[0][di][dj]);
                    acc[1][di][dj] = fdot2f(wp, s01.y, acc[1][di][dj]);
                    acc[2][di][dj] = fdot2f(wp, s23.x, acc[2][di][dj]);
                    acc[3][di][dj] = fdot2f(wp, s23.y, acc[3][di][dj]);
                    acc[4][di][dj] = fdot2f(wp, s45.x, acc[4][di][dj]);
                    acc[5][di][dj] = fdot2f(wp, s45.y, acc[5][di][dj]);
                    acc[6][di][dj] = fdot2f(wp, s67.x, acc[6][di][dj]);
                    acc[7][di][dj] = fdot2f(wp, s67.y, acc[7][di][dj]);
                    u += tg.w;
                }
            }
        }
    }

    #pragma unroll
    for (int bb = 0; bb < 8; ++bb) {
        float* ob = out + (size_t)(b + bb) * (NH * NH) + (size_t)pi * NH + pj;
        #pragma unroll
        for (int di = 0; di < 2; ++di)
            #pragma unroll
            for (int dj = 0; dj < 2; ++dj)
                unsafeAtomicAdd(ob + di * NH + dj, acc[bb][di][dj] * DPHI_F);
    }
}

// ---------------------------------------------------------------------------
extern "C" void kernel_launch(void* const* d_in, const int* in_sizes, int n_in,
                              void* d_out, int out_size, void* d_ws, size_t ws_size,
                              hipStream_t stream) {
    const float* sinos = (const float*)d_in[0];   // [32,720,512] f32
    const float* kern  = (const float*)d_in[1];   // [257] f32
    float* out = (float*)d_out;                   // [32,256,256] f32
    float* ws  = (float*)d_ws;

    // ws layout: [0,4096) f32 tables; then padded filt f32 (23040x520 = 47.9MB)
    float* filt = ws + 4096;

    hipLaunchKernelGGL(front_kernel, dim3(490), dim3(512), 0, stream,
                       sinos, kern, ws, (float4*)out, filt);
    hipLaunchKernelGGL(backproject_kernel, dim3(6 * (NB / 8) * 64), dim3(256), 0, stream,
                       filt, ws, out);
}